// Round 7
// baseline (199.931 us; speedup 1.0000x reference)
//
#include <hip/hip_runtime.h>
#include <hip/hip_bf16.h>

// out[bt,o] = b[o] + sum_{i,j} Xa[bt,i]*Xb[bt,j]*W[o, i*257+j], Xa=[1,X], Xb=[1,X_aux]
// Chunk decomposition (c in [0,258)):
//   c<256 : contrib = X[r,c] * sum_j Xb[r,j]*Bp[c][o][j]
//   c=256 : contrib =          sum_j Xb[r,j]*Bp[256][o][j]
//   c=257 : contrib =          sum_j X [r,j]*Bp[257][o][j]
// k=0 corner (W[o,0]) folded into reduce with bias.
//
// R7 (on R6's chunk-invariant-A structure): A-fragments for k-tiles 0,1
// register-cached once per block (chunk-invariant!) -> LDS read traffic
// 16->12 b128/wave/K-tile; 32-bit strength-reduced STAGE addressing;
// statically unrolled Bs ping-pong. Slice 7 reloads the cache after
// repacking As from X for c=257.

#define DI 66049

typedef __attribute__((ext_vector_type(8))) short bf16x8;
typedef __attribute__((ext_vector_type(4))) float f32x4;

__device__ __forceinline__ unsigned short f2b(float f) {
  union { __hip_bfloat16 h; unsigned short u; } cv;
  cv.h = __float2bfloat16(f);
  return cv.u;
}

__device__ __forceinline__ bf16x8 pack8(f32x4 lo, f32x4 hi) {
  bf16x8 r;
  r[0] = (short)f2b(lo[0]); r[1] = (short)f2b(lo[1]);
  r[2] = (short)f2b(lo[2]); r[3] = (short)f2b(lo[3]);
  r[4] = (short)f2b(hi[0]); r[5] = (short)f2b(hi[1]);
  r[6] = (short)f2b(hi[2]); r[7] = (short)f2b(hi[3]);
  return r;
}

__device__ __forceinline__ void gload16(const void* g, void* l) {
  __builtin_amdgcn_global_load_lds(
      (const __attribute__((address_space(1))) unsigned int*)g,
      (__attribute__((address_space(3))) unsigned int*)l, 16, 0, 0);
}

// ---- prep: gather W (f32) into bf16 Bp[c][o][j] (linear), c in [0,258)
__global__ void prep_w(const float* __restrict__ W, unsigned short* __restrict__ Bp) {
  const int c = blockIdx.x;
  const int o = (blockIdx.y << 2) + (threadIdx.x >> 6);
  const int j = (threadIdx.x & 63) << 2;
  const float* wrow = W + (size_t)o * DI;
  float v0, v1, v2, v3;
  if (c < 256) {
    const int bse = (c + 1) * 257 + 1 + j;
    v0 = wrow[bse]; v1 = wrow[bse + 1]; v2 = wrow[bse + 2]; v3 = wrow[bse + 3];
  } else if (c == 256) {
    const int bse = 1 + j;
    v0 = wrow[bse]; v1 = wrow[bse + 1]; v2 = wrow[bse + 2]; v3 = wrow[bse + 3];
  } else {
    v0 = wrow[(j + 1) * 257]; v1 = wrow[(j + 2) * 257];
    v2 = wrow[(j + 3) * 257]; v3 = wrow[(j + 4) * 257];
  }
  unsigned short* dst = Bp + (((size_t)c << 8) + o) * 256 + j;
  const unsigned int lo = (unsigned int)f2b(v0) | ((unsigned int)f2b(v1) << 16);
  const unsigned int hi = (unsigned int)f2b(v2) | ((unsigned int)f2b(v3) << 16);
  *(uint2*)dst = make_uint2(lo, hi);
}

// ---- prep: Xt[c][bt] = X[bt][c]  (f32 transpose for coalesced scale loads)
__global__ void prep_xt(const float* __restrict__ X, float* __restrict__ Xt) {
  __shared__ float t[32][33];
  const int tx = threadIdx.x, ty = threadIdx.y;
  const int bt0 = blockIdx.x << 5, c0 = blockIdx.y << 5;
#pragma unroll
  for (int k = 0; k < 4; ++k) {
    const int row = (ty << 2) + k;
    t[row][tx] = X[(size_t)(bt0 + row) * 256 + c0 + tx];
  }
  __syncthreads();
#pragma unroll
  for (int k = 0; k < 4; ++k) {
    const int row = (ty << 2) + k;
    Xt[(size_t)(c0 + row) * 4096 + bt0 + tx] = t[tx][row];
  }
}

// pack As[128][256] bf16 from SRC rows [bt0,bt0+128), 16-slot XOR swizzle
#define PACK_AS(SRC)                                                           \
  {                                                                            \
    const int _row = tid >> 2, _q = tid & 3;                                   \
    const float* _rp = (SRC) + (size_t)(bt0 + _row) * 256 + (_q << 6);         \
    const int _sx = _row & 15;                                                 \
    _Pragma("unroll") for (int _w = 0; _w < 8; ++_w) {                         \
      f32x4 _lo = *(const f32x4*)(_rp + (_w << 3));                            \
      f32x4 _hi = *(const f32x4*)(_rp + (_w << 3) + 4);                        \
      const int _slot = (_q << 3) + _w;                                        \
      *(bf16x8*)(&As[_row * 256 + ((_slot ^ _sx) << 3)]) = pack8(_lo, _hi);    \
    }                                                                          \
  }

// load chunk-invariant A-fragment register cache for k-tiles 0,1
#define LOAD_AFC()                                                             \
  {                                                                            \
    _Pragma("unroll") for (int _k4 = 0; _k4 < 2; ++_k4) {                      \
      _Pragma("unroll") for (int _rg = 0; _rg < 4; ++_rg) {                    \
        const int _ra = wr + (_rg << 4) + l15;                                 \
        const int _sx = _ra & 15;                                              \
        const int _sb = _k4 << 3;                                              \
        afc[_k4][_rg][0] =                                                     \
            *(const bf16x8*)(&As[_ra * 256 + (((_sb + lg) ^ _sx) << 3)]);      \
        afc[_k4][_rg][1] =                                                     \
            *(const bf16x8*)(&As[_ra * 256 + (((_sb + 4 + lg) ^ _sx) << 3)]);  \
      }                                                                        \
    }                                                                          \
  }

// stage one B K-tile into Bs[BUF]: 4 x gload16/thread, 32-bit offsets
#define STAGE(C, JB, BUF)                                                      \
  {                                                                            \
    const unsigned _cb = ((unsigned)(C) << 16) + (unsigned)(JB);               \
    _Pragma("unroll") for (int _e = 0; _e < 4; ++_e) {                         \
      gload16(Bp + _cb + stg_off[_e],                                          \
              &Bs[BUF][(size_t)(((_e << 9) | tid)) << 3]);                     \
    }                                                                          \
  }

// compute prefetch target (cn, jbn) for k-tile index nk = ci*4 + K4 + 1
#define NEXT_CJ(K4, CN, JBN)                                                   \
  int _nk = (ci << 2) + (K4) + 1;                                              \
  if (_nk > nkmax) _nk = nkmax;                                                \
  const int _nci = _nk >> 2;                                                   \
  const int CN = is7 ? (_nci < 32 ? 225 + _nci : 257) : c0 + _nci;             \
  const int JBN = (_nk & 3) << 6;

// one K-tile: stage next, 8 B-frag reads, 4x(2 A-frags + 8 MFMA), sync.
// A0X/A1X are expressions giving the A fragments for row-group `rg`.
#define KT(K4, CUR, A0X, A1X)                                                  \
  {                                                                            \
    NEXT_CJ(K4, _cn, _jbn);                                                    \
    STAGE(_cn, _jbn, (CUR) ^ 1);                                               \
    bf16x8 bf0[4], bf1[4];                                                     \
    _Pragma("unroll") for (int fn = 0; fn < 4; ++fn) {                         \
      const int _rb = (wn << 6) + (fn << 4) + l15;                             \
      const int _rx = _rb & 7;                                                 \
      bf0[fn] = *(const bf16x8*)(&Bs[CUR][_rb * 64 + ((lg ^ _rx) << 3)]);      \
      bf1[fn] = *(const bf16x8*)(&Bs[CUR][_rb * 64 + (((4 + lg) ^ _rx) << 3)]);\
    }                                                                          \
    _Pragma("unroll") for (int rg = 0; rg < 4; ++rg) {                         \
      bf16x8 _a0 = (A0X);                                                      \
      bf16x8 _a1 = (A1X);                                                      \
      _Pragma("unroll") for (int fn = 0; fn < 4; ++fn) {                       \
        t[rg][fn] = __builtin_amdgcn_mfma_f32_16x16x32_bf16(_a0, bf0[fn],      \
                                                            t[rg][fn], 0, 0, 0); \
        t[rg][fn] = __builtin_amdgcn_mfma_f32_16x16x32_bf16(_a1, bf1[fn],      \
                                                            t[rg][fn], 0, 0, 0); \
      }                                                                        \
    }                                                                          \
    __syncthreads();                                                           \
  }

// LDS A-fragment read expressions (k-tiles 2,3)
#define ALDS(K4, HALF)                                                         \
  (*(const bf16x8*)(&As[(wr + (rg << 4) + l15) * 256 +                         \
                        (((((K4) << 3) + (HALF)*4 + lg) ^                      \
                          ((wr + (rg << 4) + l15) & 15))                       \
                         << 3)]))

__global__ __launch_bounds__(512, 2) void gemm_r7(
    const float* __restrict__ X, const float* __restrict__ Xb,
    const float* __restrict__ Xt, const unsigned short* __restrict__ Bp,
    float* __restrict__ P) {
  __shared__ __align__(16) unsigned short As[128 * 256];     // 64 KB static A
  __shared__ __align__(16) unsigned short Bs[2][256 * 64];   // 2 x 32 KB dbuf

  const int tid = threadIdx.x;
  const int rid = blockIdx.x;
  const int slice = rid & 7;   // slice pinned to XCD (rid%8 round-robin)
  const int bx = rid >> 3;
  const int bt0 = bx << 7;
  const bool is7 = (slice == 7);
  // slices 0..6 split c in [0,225): 33,32,32,32,32,32,32 ; slice 7: [225,257)+{257}
  const int c0 = is7 ? 225 : slice * 32 + (slice ? 1 : 0);
  const int nCh = (slice == 0 || is7) ? 33 : 32;
  const int nkmax = (nCh << 2) - 1;

  const int wid = tid >> 6, lane = tid & 63;
  const int wm = wid >> 2, wn = wid & 3;  // 2 (bt) x 4 (o) waves
  const int wr = wm << 6;
  const int l15 = lane & 15, lg = lane >> 4;

  // per-thread STAGE source offsets (row*256 + swizzled-slot*8), 32-bit
  unsigned stg_off[4];
#pragma unroll
  for (int e = 0; e < 4; ++e) {
    const int row = (e << 6) | (tid >> 3);
    const int sl = (tid & 7) ^ (row & 7);
    stg_off[e] = (unsigned)(row * 256 + (sl << 3));
  }

  PACK_AS(Xb);
  STAGE(c0, 0, 0);
  __syncthreads();

  bf16x8 afc[2][4][2];
  LOAD_AFC();

  f32x4 acc[4][4] = {};

  for (int ci = 0; ci < nCh; ++ci) {
    const int c = is7 ? (ci < 32 ? 225 + ci : 257) : c0 + ci;

    f32x4 t[4][4] = {};
    KT(0, 0, afc[0][rg][0], afc[0][rg][1]);
    KT(1, 1, afc[1][rg][0], afc[1][rg][1]);
    KT(2, 0, ALDS(2, 0), ALDS(2, 1));
    KT(3, 1, ALDS(3, 0), ALDS(3, 1));

    // scales for this chunk (f32; rows match C-layout rows)
    f32x4 s4[4];
    if (c < 256) {
      const float* sp = Xt + (size_t)c * 4096 + bt0 + wr + (lg << 2);
#pragma unroll
      for (int rg = 0; rg < 4; ++rg) s4[rg] = *(const f32x4*)(sp + (rg << 4));
    } else {
#pragma unroll
      for (int rg = 0; rg < 4; ++rg) s4[rg] = (f32x4){1.f, 1.f, 1.f, 1.f};
    }
#pragma unroll
    for (int rg = 0; rg < 4; ++rg)
#pragma unroll
      for (int fn = 0; fn < 4; ++fn) acc[rg][fn] += s4[rg] * t[rg][fn];

    if (is7 && ci == 31) {  // switch A-operand to X for the c=257 chunk
      __syncthreads();
      PACK_AS(X);
      __syncthreads();
      LOAD_AFC();
    }
  }

  // ---- epilogue: C layout col = lane&15, row = (lane>>4)*4 + reg
  float* pp = P + ((size_t)slice << 20);
#pragma unroll
  for (int rg = 0; rg < 4; ++rg) {
    const int row = bt0 + wr + (rg << 4) + (lg << 2);
#pragma unroll
    for (int fn = 0; fn < 4; ++fn) {
      const int col = (wn << 6) + (fn << 4) + l15;
#pragma unroll
      for (int e = 0; e < 4; ++e)
        pp[(size_t)(row + e) * 256 + col] = acc[rg][fn][e];
    }
  }
}

// ---- reduce: sum 8 partial slices + bias + W[o,0]
__global__ void reduce_k(const float* __restrict__ P, const float* __restrict__ W,
                         const float* __restrict__ b, float* __restrict__ out,
                         int nsl) {
  const int idx = blockIdx.x * 256 + threadIdx.x;
  const int o = idx & 255;
  float v = b[o] + W[(size_t)o * DI];
  for (int s = 0; s < nsl; ++s) v += P[idx + (size_t)s * 1048576];
  out[idx] = v;
}

// ================= fallback path (tiny ws): R2 proven kernels ================
__global__ void init_k(const float* __restrict__ W, const float* __restrict__ b,
                       float* __restrict__ out) {
  const int idx = blockIdx.x * 256 + threadIdx.x;
  const int o = idx & 255;
  out[idx] = b[o] + W[(size_t)o * DI];
}

__global__ __launch_bounds__(256, 4) void gemm_fb(
    const float* __restrict__ X, const float* __restrict__ Xa,
    const float* __restrict__ W, float* __restrict__ Out) {
  __shared__ __align__(16) unsigned short Asf[128 * 64];
  __shared__ __align__(16) unsigned short Bsf[128 * 64];
  const int tid = threadIdx.x;
  const int bx = blockIdx.x, by = blockIdx.y, bz = blockIdx.z;
  const int S = gridDim.z;
  const int bt0 = bx << 7, o0 = by << 7;
  const int q = 258 / S, r = 258 % S;
  const int c0 = bz * q + (bz < r ? bz : r);
  const int ccnt = q + (bz < r ? 1 : 0);
  const int nK = ccnt << 2;
  const int wid = tid >> 6, lane = tid & 63;
  const int wr = (wid >> 1) << 6, wc = (wid & 1) << 6;
  const int ar = tid >> 1;
  const int ah = (tid & 1) << 5;
  const float* xrow = X + (size_t)(bt0 + ar) * 256;
  const float* varow = Xa + (size_t)(bt0 + ar) * 256;
  f32x4 acc[4][4] = {};
  for (int kt = 0; kt < nK; ++kt) {
    const int c = c0 + (kt >> 2);
    const int j0 = (kt & 3) << 6;
    __syncthreads();
    {
      const float* vs = (c == 257) ? xrow : varow;
      float s = 1.0f;
      if (c < 256) s = xrow[c];
      const f32x4* vp = (const f32x4*)(vs + j0 + ah);
      f32x4 v[8];
#pragma unroll
      for (int qq = 0; qq < 8; ++qq) v[qq] = vp[qq];
      unsigned short* aw = Asf + ar * 64;
      const int sl0 = ah >> 3, sx = ar & 7;
#pragma unroll
      for (int w = 0; w < 4; ++w) {
        bf16x8 pk;
#pragma unroll
        for (int e = 0; e < 8; ++e)
          pk[e] = (short)f2b(s * v[w * 2 + (e >> 2)][e & 3]);
        *(bf16x8*)(aw + (((sl0 + w) ^ sx) << 3)) = pk;
      }
    }
    {
      const int orow = tid >> 1;
      const int jh = (tid & 1) << 5;
      const float* wrow = W + (size_t)(o0 + orow) * DI;
      float tmp[32];
      if (c < 256) {
        const int bse = (c + 1) * 257 + 1 + j0 + jh;
#pragma unroll
        for (int i = 0; i < 32; ++i) tmp[i] = wrow[bse + i];
      } else if (c == 256) {
        const int bse = 1 + j0 + jh;
#pragma unroll
        for (int i = 0; i < 32; ++i) tmp[i] = wrow[bse + i];
      } else {
#pragma unroll
        for (int i = 0; i < 32; ++i) tmp[i] = wrow[(j0 + jh + i + 1) * 257];
      }
      unsigned short* bw = Bsf + orow * 64;
      const int sl0 = jh >> 3, sx = orow & 7;
#pragma unroll
      for (int w = 0; w < 4; ++w) {
        bf16x8 pk;
#pragma unroll
        for (int e = 0; e < 8; ++e) pk[e] = (short)f2b(tmp[w * 8 + e]);
        *(bf16x8*)(bw + (((sl0 + w) ^ sx) << 3)) = pk;
      }
    }
    __syncthreads();
#pragma unroll
    for (int kk = 0; kk < 2; ++kk) {
      const int kslot = (kk << 2) + (lane >> 4);
      bf16x8 af[4], bfr2[4];
#pragma unroll
      for (int fm = 0; fm < 4; ++fm) {
        const int row = wr + (fm << 4) + (lane & 15);
        af[fm] = *(const bf16x8*)(Asf + row * 64 + ((kslot ^ (row & 7)) << 3));
      }
#pragma unroll
      for (int fn = 0; fn < 4; ++fn) {
        const int row = wc + (fn << 4) + (lane & 15);
        bfr2[fn] = *(const bf16x8*)(Bsf + row * 64 + ((kslot ^ (row & 7)) << 3));
      }
#pragma unroll
      for (int fm = 0; fm < 4; ++fm)
#pragma unroll
        for (int fn = 0; fn < 4; ++fn)
          acc[fm][fn] = __builtin_amdgcn_mfma_f32_16x16x32_bf16(
              af[fm], bfr2[fn], acc[fm][fn], 0, 0, 0);
    }
  }
  const int r0 = (lane >> 4) << 2;
  const int cl = lane & 15;
#pragma unroll
  for (int fm = 0; fm < 4; ++fm) {
    const int row = bt0 + wr + (fm << 4) + r0;
#pragma unroll
    for (int fn = 0; fn < 4; ++fn) {
      const int col = o0 + wc + (fn << 4) + cl;
#pragma unroll
      for (int rr = 0; rr < 4; ++rr)
        atomicAdd(Out + (size_t)(row + rr) * 256 + col, acc[fm][fn][rr]);
    }
  }
}

extern "C" void kernel_launch(void* const* d_in, const int* in_sizes, int n_in,
                              void* d_out, int out_size, void* d_ws, size_t ws_size,
                              hipStream_t stream) {
  const float* X  = (const float*)d_in[0];
  const float* Xa = (const float*)d_in[1];
  const float* W  = (const float*)d_in[2];
  const float* b  = (const float*)d_in[3];
  float* out = (float*)d_out;

  const size_t WBF_SZ = (size_t)258 * 256 * 256 * 2;  // 33,816,576 B
  const size_t XT_SZ  = (size_t)256 * 4096 * 4;       //  4,194,304 B
  const size_t PART1  = (size_t)4096 * 256 * 4;       //  4 MiB per slice

  if (ws_size >= WBF_SZ + XT_SZ + 8 * PART1) {
    unsigned short* Bp = (unsigned short*)d_ws;
    float* Xt = (float*)((char*)d_ws + WBF_SZ);
    float* P  = (float*)((char*)d_ws + WBF_SZ + XT_SZ);
    prep_w<<<dim3(258, 64), 256, 0, stream>>>(W, Bp);
    prep_xt<<<dim3(128, 8), dim3(32, 8), 0, stream>>>(X, Xt);
    gemm_r7<<<dim3(256), 512, 0, stream>>>(X, Xa, Xt, Bp, P);
    reduce_k<<<4096, 256, 0, stream>>>(P, W, b, out, 8);
  } else {
    init_k<<<4096, 256, 0, stream>>>(W, b, out);
    gemm_fb<<<dim3(32, 2, 4), 256, 0, stream>>>(X, Xa, W, out);
  }
}

// Round 8
// 199.910 us; speedup vs baseline: 1.0001x; 1.0001x over previous
//
#include <hip/hip_runtime.h>
#include <hip/hip_bf16.h>

// out[bt,o] = b[o] + sum_{i,j} Xa[bt,i]*Xb[bt,j]*W[o, i*257+j], Xa=[1,X], Xb=[1,X_aux]
// Chunk decomposition (c in [0,258)):
//   c<256 : contrib = X[r,c] * sum_j Xb[r,j]*Bp[c][o][j]
//   c=256 : contrib =          sum_j Xb[r,j]*Bp[256][o][j]
//   c=257 : contrib =          sum_j X [r,j]*Bp[257][o][j]
// k=0 corner (W[o,0]) folded into reduce with bias.
//
// R8 = R7 with __launch_bounds__(512, 1): LDS (128KB) already limits to
// 1 block/CU, so the previous (512,2) only served to cap VGPR at 128 and
// spill the chunk-invariant A-fragment register cache to scratch
// (WRITE_SIZE 37->49MB). With a 256-VGPR cap the afc cache (64 VGPR) fits:
// LDS read traffic 16->12 b128/wave/K-tile, no scratch.

#define DI 66049

typedef __attribute__((ext_vector_type(8))) short bf16x8;
typedef __attribute__((ext_vector_type(4))) float f32x4;

__device__ __forceinline__ unsigned short f2b(float f) {
  union { __hip_bfloat16 h; unsigned short u; } cv;
  cv.h = __float2bfloat16(f);
  return cv.u;
}

__device__ __forceinline__ bf16x8 pack8(f32x4 lo, f32x4 hi) {
  bf16x8 r;
  r[0] = (short)f2b(lo[0]); r[1] = (short)f2b(lo[1]);
  r[2] = (short)f2b(lo[2]); r[3] = (short)f2b(lo[3]);
  r[4] = (short)f2b(hi[0]); r[5] = (short)f2b(hi[1]);
  r[6] = (short)f2b(hi[2]); r[7] = (short)f2b(hi[3]);
  return r;
}

__device__ __forceinline__ void gload16(const void* g, void* l) {
  __builtin_amdgcn_global_load_lds(
      (const __attribute__((address_space(1))) unsigned int*)g,
      (__attribute__((address_space(3))) unsigned int*)l, 16, 0, 0);
}

// ---- prep: gather W (f32) into bf16 Bp[c][o][j] (linear), c in [0,258)
__global__ void prep_w(const float* __restrict__ W, unsigned short* __restrict__ Bp) {
  const int c = blockIdx.x;
  const int o = (blockIdx.y << 2) + (threadIdx.x >> 6);
  const int j = (threadIdx.x & 63) << 2;
  const float* wrow = W + (size_t)o * DI;
  float v0, v1, v2, v3;
  if (c < 256) {
    const int bse = (c + 1) * 257 + 1 + j;
    v0 = wrow[bse]; v1 = wrow[bse + 1]; v2 = wrow[bse + 2]; v3 = wrow[bse + 3];
  } else if (c == 256) {
    const int bse = 1 + j;
    v0 = wrow[bse]; v1 = wrow[bse + 1]; v2 = wrow[bse + 2]; v3 = wrow[bse + 3];
  } else {
    v0 = wrow[(j + 1) * 257]; v1 = wrow[(j + 2) * 257];
    v2 = wrow[(j + 3) * 257]; v3 = wrow[(j + 4) * 257];
  }
  unsigned short* dst = Bp + (((size_t)c << 8) + o) * 256 + j;
  const unsigned int lo = (unsigned int)f2b(v0) | ((unsigned int)f2b(v1) << 16);
  const unsigned int hi = (unsigned int)f2b(v2) | ((unsigned int)f2b(v3) << 16);
  *(uint2*)dst = make_uint2(lo, hi);
}

// ---- prep: Xt[c][bt] = X[bt][c]  (f32 transpose for coalesced scale loads)
__global__ void prep_xt(const float* __restrict__ X, float* __restrict__ Xt) {
  __shared__ float t[32][33];
  const int tx = threadIdx.x, ty = threadIdx.y;
  const int bt0 = blockIdx.x << 5, c0 = blockIdx.y << 5;
#pragma unroll
  for (int k = 0; k < 4; ++k) {
    const int row = (ty << 2) + k;
    t[row][tx] = X[(size_t)(bt0 + row) * 256 + c0 + tx];
  }
  __syncthreads();
#pragma unroll
  for (int k = 0; k < 4; ++k) {
    const int row = (ty << 2) + k;
    Xt[(size_t)(c0 + row) * 4096 + bt0 + tx] = t[tx][row];
  }
}

// pack As[128][256] bf16 from SRC rows [bt0,bt0+128), 16-slot XOR swizzle
#define PACK_AS(SRC)                                                           \
  {                                                                            \
    const int _row = tid >> 2, _q = tid & 3;                                   \
    const float* _rp = (SRC) + (size_t)(bt0 + _row) * 256 + (_q << 6);         \
    const int _sx = _row & 15;                                                 \
    _Pragma("unroll") for (int _w = 0; _w < 8; ++_w) {                         \
      f32x4 _lo = *(const f32x4*)(_rp + (_w << 3));                            \
      f32x4 _hi = *(const f32x4*)(_rp + (_w << 3) + 4);                        \
      const int _slot = (_q << 3) + _w;                                        \
      *(bf16x8*)(&As[_row * 256 + ((_slot ^ _sx) << 3)]) = pack8(_lo, _hi);    \
    }                                                                          \
  }

// load chunk-invariant A-fragment register cache for k-tiles 0,1
#define LOAD_AFC()                                                             \
  {                                                                            \
    _Pragma("unroll") for (int _k4 = 0; _k4 < 2; ++_k4) {                      \
      _Pragma("unroll") for (int _rg = 0; _rg < 4; ++_rg) {                    \
        const int _ra = wr + (_rg << 4) + l15;                                 \
        const int _sx = _ra & 15;                                              \
        const int _sb = _k4 << 3;                                              \
        afc[_k4][_rg][0] =                                                     \
            *(const bf16x8*)(&As[_ra * 256 + (((_sb + lg) ^ _sx) << 3)]);      \
        afc[_k4][_rg][1] =                                                     \
            *(const bf16x8*)(&As[_ra * 256 + (((_sb + 4 + lg) ^ _sx) << 3)]);  \
      }                                                                        \
    }                                                                          \
  }

// stage one B K-tile into Bs[BUF]: 4 x gload16/thread, 32-bit offsets
#define STAGE(C, JB, BUF)                                                      \
  {                                                                            \
    const unsigned _cb = ((unsigned)(C) << 16) + (unsigned)(JB);               \
    _Pragma("unroll") for (int _e = 0; _e < 4; ++_e) {                         \
      gload16(Bp + _cb + stg_off[_e],                                          \
              &Bs[BUF][(size_t)(((_e << 9) | tid)) << 3]);                     \
    }                                                                          \
  }

// compute prefetch target (cn, jbn) for k-tile index nk = ci*4 + K4 + 1
#define NEXT_CJ(K4, CN, JBN)                                                   \
  int _nk = (ci << 2) + (K4) + 1;                                              \
  if (_nk > nkmax) _nk = nkmax;                                                \
  const int _nci = _nk >> 2;                                                   \
  const int CN = is7 ? (_nci < 32 ? 225 + _nci : 257) : c0 + _nci;             \
  const int JBN = (_nk & 3) << 6;

// one K-tile: stage next, 8 B-frag reads, 4x(2 A-frags + 8 MFMA), sync.
// A0X/A1X are expressions giving the A fragments for row-group `rg`.
#define KT(K4, CUR, A0X, A1X)                                                  \
  {                                                                            \
    NEXT_CJ(K4, _cn, _jbn);                                                    \
    STAGE(_cn, _jbn, (CUR) ^ 1);                                               \
    bf16x8 bf0[4], bf1[4];                                                     \
    _Pragma("unroll") for (int fn = 0; fn < 4; ++fn) {                         \
      const int _rb = (wn << 6) + (fn << 4) + l15;                             \
      const int _rx = _rb & 7;                                                 \
      bf0[fn] = *(const bf16x8*)(&Bs[CUR][_rb * 64 + ((lg ^ _rx) << 3)]);      \
      bf1[fn] = *(const bf16x8*)(&Bs[CUR][_rb * 64 + (((4 + lg) ^ _rx) << 3)]);\
    }                                                                          \
    _Pragma("unroll") for (int rg = 0; rg < 4; ++rg) {                         \
      bf16x8 _a0 = (A0X);                                                      \
      bf16x8 _a1 = (A1X);                                                      \
      _Pragma("unroll") for (int fn = 0; fn < 4; ++fn) {                       \
        t[rg][fn] = __builtin_amdgcn_mfma_f32_16x16x32_bf16(_a0, bf0[fn],      \
                                                            t[rg][fn], 0, 0, 0); \
        t[rg][fn] = __builtin_amdgcn_mfma_f32_16x16x32_bf16(_a1, bf1[fn],      \
                                                            t[rg][fn], 0, 0, 0); \
      }                                                                        \
    }                                                                          \
    __syncthreads();                                                           \
  }

// LDS A-fragment read expressions (k-tiles 2,3)
#define ALDS(K4, HALF)                                                         \
  (*(const bf16x8*)(&As[(wr + (rg << 4) + l15) * 256 +                         \
                        (((((K4) << 3) + (HALF)*4 + lg) ^                      \
                          ((wr + (rg << 4) + l15) & 15))                       \
                         << 3)]))

__global__ __launch_bounds__(512, 1) void gemm_r8(
    const float* __restrict__ X, const float* __restrict__ Xb,
    const float* __restrict__ Xt, const unsigned short* __restrict__ Bp,
    float* __restrict__ P) {
  __shared__ __align__(16) unsigned short As[128 * 256];     // 64 KB static A
  __shared__ __align__(16) unsigned short Bs[2][256 * 64];   // 2 x 32 KB dbuf

  const int tid = threadIdx.x;
  const int rid = blockIdx.x;
  const int slice = rid & 7;   // slice pinned to XCD (rid%8 round-robin)
  const int bx = rid >> 3;
  const int bt0 = bx << 7;
  const bool is7 = (slice == 7);
  // slices 0..6 split c in [0,225): 33,32,32,32,32,32,32 ; slice 7: [225,257)+{257}
  const int c0 = is7 ? 225 : slice * 32 + (slice ? 1 : 0);
  const int nCh = (slice == 0 || is7) ? 33 : 32;
  const int nkmax = (nCh << 2) - 1;

  const int wid = tid >> 6, lane = tid & 63;
  const int wm = wid >> 2, wn = wid & 3;  // 2 (bt) x 4 (o) waves
  const int wr = wm << 6;
  const int l15 = lane & 15, lg = lane >> 4;

  // per-thread STAGE source offsets (row*256 + swizzled-slot*8), 32-bit
  unsigned stg_off[4];
#pragma unroll
  for (int e = 0; e < 4; ++e) {
    const int row = (e << 6) | (tid >> 3);
    const int sl = (tid & 7) ^ (row & 7);
    stg_off[e] = (unsigned)(row * 256 + (sl << 3));
  }

  PACK_AS(Xb);
  STAGE(c0, 0, 0);
  __syncthreads();

  bf16x8 afc[2][4][2];
  LOAD_AFC();

  f32x4 acc[4][4] = {};

  for (int ci = 0; ci < nCh; ++ci) {
    const int c = is7 ? (ci < 32 ? 225 + ci : 257) : c0 + ci;

    f32x4 t[4][4] = {};
    KT(0, 0, afc[0][rg][0], afc[0][rg][1]);
    KT(1, 1, afc[1][rg][0], afc[1][rg][1]);
    KT(2, 0, ALDS(2, 0), ALDS(2, 1));
    KT(3, 1, ALDS(3, 0), ALDS(3, 1));

    // scales for this chunk (f32; rows match C-layout rows)
    f32x4 s4[4];
    if (c < 256) {
      const float* sp = Xt + (size_t)c * 4096 + bt0 + wr + (lg << 2);
#pragma unroll
      for (int rg = 0; rg < 4; ++rg) s4[rg] = *(const f32x4*)(sp + (rg << 4));
    } else {
#pragma unroll
      for (int rg = 0; rg < 4; ++rg) s4[rg] = (f32x4){1.f, 1.f, 1.f, 1.f};
    }
#pragma unroll
    for (int rg = 0; rg < 4; ++rg)
#pragma unroll
      for (int fn = 0; fn < 4; ++fn) acc[rg][fn] += s4[rg] * t[rg][fn];

    if (is7 && ci == 31) {  // switch A-operand to X for the c=257 chunk
      __syncthreads();
      PACK_AS(X);
      __syncthreads();
      LOAD_AFC();
    }
  }

  // ---- epilogue: C layout col = lane&15, row = (lane>>4)*4 + reg
  float* pp = P + ((size_t)slice << 20);
#pragma unroll
  for (int rg = 0; rg < 4; ++rg) {
    const int row = bt0 + wr + (rg << 4) + (lg << 2);
#pragma unroll
    for (int fn = 0; fn < 4; ++fn) {
      const int col = (wn << 6) + (fn << 4) + l15;
#pragma unroll
      for (int e = 0; e < 4; ++e)
        pp[(size_t)(row + e) * 256 + col] = acc[rg][fn][e];
    }
  }
}

// ---- reduce: sum 8 partial slices + bias + W[o,0]
__global__ void reduce_k(const float* __restrict__ P, const float* __restrict__ W,
                         const float* __restrict__ b, float* __restrict__ out,
                         int nsl) {
  const int idx = blockIdx.x * 256 + threadIdx.x;
  const int o = idx & 255;
  float v = b[o] + W[(size_t)o * DI];
  for (int s = 0; s < nsl; ++s) v += P[idx + (size_t)s * 1048576];
  out[idx] = v;
}

// ================= fallback path (tiny ws): R2 proven kernels ================
__global__ void init_k(const float* __restrict__ W, const float* __restrict__ b,
                       float* __restrict__ out) {
  const int idx = blockIdx.x * 256 + threadIdx.x;
  const int o = idx & 255;
  out[idx] = b[o] + W[(size_t)o * DI];
}

__global__ __launch_bounds__(256, 4) void gemm_fb(
    const float* __restrict__ X, const float* __restrict__ Xa,
    const float* __restrict__ W, float* __restrict__ Out) {
  __shared__ __align__(16) unsigned short Asf[128 * 64];
  __shared__ __align__(16) unsigned short Bsf[128 * 64];
  const int tid = threadIdx.x;
  const int bx = blockIdx.x, by = blockIdx.y, bz = blockIdx.z;
  const int S = gridDim.z;
  const int bt0 = bx << 7, o0 = by << 7;
  const int q = 258 / S, r = 258 % S;
  const int c0 = bz * q + (bz < r ? bz : r);
  const int ccnt = q + (bz < r ? 1 : 0);
  const int nK = ccnt << 2;
  const int wid = tid >> 6, lane = tid & 63;
  const int wr = (wid >> 1) << 6, wc = (wid & 1) << 6;
  const int ar = tid >> 1;
  const int ah = (tid & 1) << 5;
  const float* xrow = X + (size_t)(bt0 + ar) * 256;
  const float* varow = Xa + (size_t)(bt0 + ar) * 256;
  f32x4 acc[4][4] = {};
  for (int kt = 0; kt < nK; ++kt) {
    const int c = c0 + (kt >> 2);
    const int j0 = (kt & 3) << 6;
    __syncthreads();
    {
      const float* vs = (c == 257) ? xrow : varow;
      float s = 1.0f;
      if (c < 256) s = xrow[c];
      const f32x4* vp = (const f32x4*)(vs + j0 + ah);
      f32x4 v[8];
#pragma unroll
      for (int qq = 0; qq < 8; ++qq) v[qq] = vp[qq];
      unsigned short* aw = Asf + ar * 64;
      const int sl0 = ah >> 3, sx = ar & 7;
#pragma unroll
      for (int w = 0; w < 4; ++w) {
        bf16x8 pk;
#pragma unroll
        for (int e = 0; e < 8; ++e)
          pk[e] = (short)f2b(s * v[w * 2 + (e >> 2)][e & 3]);
        *(bf16x8*)(aw + (((sl0 + w) ^ sx) << 3)) = pk;
      }
    }
    {
      const int orow = tid >> 1;
      const int jh = (tid & 1) << 5;
      const float* wrow = W + (size_t)(o0 + orow) * DI;
      float tmp[32];
      if (c < 256) {
        const int bse = (c + 1) * 257 + 1 + j0 + jh;
#pragma unroll
        for (int i = 0; i < 32; ++i) tmp[i] = wrow[bse + i];
      } else if (c == 256) {
        const int bse = 1 + j0 + jh;
#pragma unroll
        for (int i = 0; i < 32; ++i) tmp[i] = wrow[bse + i];
      } else {
#pragma unroll
        for (int i = 0; i < 32; ++i) tmp[i] = wrow[(j0 + jh + i + 1) * 257];
      }
      unsigned short* bw = Bsf + orow * 64;
      const int sl0 = jh >> 3, sx = orow & 7;
#pragma unroll
      for (int w = 0; w < 4; ++w) {
        bf16x8 pk;
#pragma unroll
        for (int e = 0; e < 8; ++e) pk[e] = (short)f2b(tmp[w * 8 + e]);
        *(bf16x8*)(bw + (((sl0 + w) ^ sx) << 3)) = pk;
      }
    }
    __syncthreads();
#pragma unroll
    for (int kk = 0; kk < 2; ++kk) {
      const int kslot = (kk << 2) + (lane >> 4);
      bf16x8 af[4], bfr2[4];
#pragma unroll
      for (int fm = 0; fm < 4; ++fm) {
        const int row = wr + (fm << 4) + (lane & 15);
        af[fm] = *(const bf16x8*)(Asf + row * 64 + ((kslot ^ (row & 7)) << 3));
      }
#pragma unroll
      for (int fn = 0; fn < 4; ++fn) {
        const int row = wc + (fn << 4) + (lane & 15);
        bfr2[fn] = *(const bf16x8*)(Bsf + row * 64 + ((kslot ^ (row & 7)) << 3));
      }
#pragma unroll
      for (int fm = 0; fm < 4; ++fm)
#pragma unroll
        for (int fn = 0; fn < 4; ++fn)
          acc[fm][fn] = __builtin_amdgcn_mfma_f32_16x16x32_bf16(
              af[fm], bfr2[fn], acc[fm][fn], 0, 0, 0);
    }
  }
  const int r0 = (lane >> 4) << 2;
  const int cl = lane & 15;
#pragma unroll
  for (int fm = 0; fm < 4; ++fm) {
    const int row = bt0 + wr + (fm << 4) + r0;
#pragma unroll
    for (int fn = 0; fn < 4; ++fn) {
      const int col = o0 + wc + (fn << 4) + cl;
#pragma unroll
      for (int rr = 0; rr < 4; ++rr)
        atomicAdd(Out + (size_t)(row + rr) * 256 + col, acc[fm][fn][rr]);
    }
  }
}

extern "C" void kernel_launch(void* const* d_in, const int* in_sizes, int n_in,
                              void* d_out, int out_size, void* d_ws, size_t ws_size,
                              hipStream_t stream) {
  const float* X  = (const float*)d_in[0];
  const float* Xa = (const float*)d_in[1];
  const float* W  = (const float*)d_in[2];
  const float* b  = (const float*)d_in[3];
  float* out = (float*)d_out;

  const size_t WBF_SZ = (size_t)258 * 256 * 256 * 2;  // 33,816,576 B
  const size_t XT_SZ  = (size_t)256 * 4096 * 4;       //  4,194,304 B
  const size_t PART1  = (size_t)4096 * 256 * 4;       //  4 MiB per slice

  if (ws_size >= WBF_SZ + XT_SZ + 8 * PART1) {
    unsigned short* Bp = (unsigned short*)d_ws;
    float* Xt = (float*)((char*)d_ws + WBF_SZ);
    float* P  = (float*)((char*)d_ws + WBF_SZ + XT_SZ);
    prep_w<<<dim3(258, 64), 256, 0, stream>>>(W, Bp);
    prep_xt<<<dim3(128, 8), dim3(32, 8), 0, stream>>>(X, Xt);
    gemm_r8<<<dim3(256), 512, 0, stream>>>(X, Xa, Xt, Bp, P);
    reduce_k<<<4096, 256, 0, stream>>>(P, W, b, out, 8);
  } else {
    init_k<<<4096, 256, 0, stream>>>(W, b, out);
    gemm_fb<<<dim3(32, 2, 4), 256, 0, stream>>>(X, Xa, W, out);
  }
}

// Round 9
// 183.754 us; speedup vs baseline: 1.0880x; 1.0879x over previous
//
#include <hip/hip_runtime.h>
#include <hip/hip_bf16.h>

// out[bt,o] = b[o] + sum_{i,j} Xa[bt,i]*Xb[bt,j]*W[o, i*257+j], Xa=[1,X], Xb=[1,X_aux]
// Chunk decomposition (c in [0,258)):
//   c<256 : contrib = X[r,c] * sum_j Xb[r,j]*Bp[c][o][j]
//   c=256 : contrib =          sum_j Xb[r,j]*Bp[256][o][j]
//   c=257 : contrib =          sum_j X [r,j]*Bp[257][o][j]
// k=0 corner (W[o,0]) folded into reduce with bias.
//
// R9 (on R6's chunk-invariant-A structure; afc cache dropped — 2 waves/SIMD
// caps 256 unified regs/wave and acc+t already use them):
//  - raw s_barrier + counted vmcnt(4) per K-tile (no vmcnt(0) drain; prev
//    tile's stage loads have a full-K-tile lead)
//  - zero global loads in main loop: chunk scales pre-staged to LDS Ss
//    (33x128 f32, 17KB; LDS total 145KB) and read via broadcast ds_read
//    inside phase 3, hidden under MFMA
//  - setprio(1) around MFMA cluster

#define DI 66049

typedef __attribute__((ext_vector_type(8))) short bf16x8;
typedef __attribute__((ext_vector_type(4))) float f32x4;

__device__ __forceinline__ unsigned short f2b(float f) {
  union { __hip_bfloat16 h; unsigned short u; } cv;
  cv.h = __float2bfloat16(f);
  return cv.u;
}

__device__ __forceinline__ bf16x8 pack8(f32x4 lo, f32x4 hi) {
  bf16x8 r;
  r[0] = (short)f2b(lo[0]); r[1] = (short)f2b(lo[1]);
  r[2] = (short)f2b(lo[2]); r[3] = (short)f2b(lo[3]);
  r[4] = (short)f2b(hi[0]); r[5] = (short)f2b(hi[1]);
  r[6] = (short)f2b(hi[2]); r[7] = (short)f2b(hi[3]);
  return r;
}

__device__ __forceinline__ void gload16(const void* g, void* l) {
  __builtin_amdgcn_global_load_lds(
      (const __attribute__((address_space(1))) unsigned int*)g,
      (__attribute__((address_space(3))) unsigned int*)l, 16, 0, 0);
}

// ---- prep: gather W (f32) into bf16 Bp[c][o][j] (linear), c in [0,258)
__global__ void prep_w(const float* __restrict__ W, unsigned short* __restrict__ Bp) {
  const int c = blockIdx.x;
  const int o = (blockIdx.y << 2) + (threadIdx.x >> 6);
  const int j = (threadIdx.x & 63) << 2;
  const float* wrow = W + (size_t)o * DI;
  float v0, v1, v2, v3;
  if (c < 256) {
    const int bse = (c + 1) * 257 + 1 + j;
    v0 = wrow[bse]; v1 = wrow[bse + 1]; v2 = wrow[bse + 2]; v3 = wrow[bse + 3];
  } else if (c == 256) {
    const int bse = 1 + j;
    v0 = wrow[bse]; v1 = wrow[bse + 1]; v2 = wrow[bse + 2]; v3 = wrow[bse + 3];
  } else {
    v0 = wrow[(j + 1) * 257]; v1 = wrow[(j + 2) * 257];
    v2 = wrow[(j + 3) * 257]; v3 = wrow[(j + 4) * 257];
  }
  unsigned short* dst = Bp + (((size_t)c << 8) + o) * 256 + j;
  const unsigned int lo = (unsigned int)f2b(v0) | ((unsigned int)f2b(v1) << 16);
  const unsigned int hi = (unsigned int)f2b(v2) | ((unsigned int)f2b(v3) << 16);
  *(uint2*)dst = make_uint2(lo, hi);
}

// ---- prep: Xt[c][bt] = X[bt][c]  (f32 transpose for coalesced scale loads)
__global__ void prep_xt(const float* __restrict__ X, float* __restrict__ Xt) {
  __shared__ float t[32][33];
  const int tx = threadIdx.x, ty = threadIdx.y;
  const int bt0 = blockIdx.x << 5, c0 = blockIdx.y << 5;
#pragma unroll
  for (int k = 0; k < 4; ++k) {
    const int row = (ty << 2) + k;
    t[row][tx] = X[(size_t)(bt0 + row) * 256 + c0 + tx];
  }
  __syncthreads();
#pragma unroll
  for (int k = 0; k < 4; ++k) {
    const int row = (ty << 2) + k;
    Xt[(size_t)(c0 + row) * 4096 + bt0 + tx] = t[tx][row];
  }
}

// pack As[128][256] bf16 from SRC rows [bt0,bt0+128), 16-slot XOR swizzle
#define PACK_AS(SRC)                                                           \
  {                                                                            \
    const int _row = tid >> 2, _q = tid & 3;                                   \
    const float* _rp = (SRC) + (size_t)(bt0 + _row) * 256 + (_q << 6);         \
    const int _sx = _row & 15;                                                 \
    _Pragma("unroll") for (int _w = 0; _w < 8; ++_w) {                         \
      f32x4 _lo = *(const f32x4*)(_rp + (_w << 3));                            \
      f32x4 _hi = *(const f32x4*)(_rp + (_w << 3) + 4);                        \
      const int _slot = (_q << 3) + _w;                                        \
      *(bf16x8*)(&As[_row * 256 + ((_slot ^ _sx) << 3)]) = pack8(_lo, _hi);    \
    }                                                                          \
  }

// stage one B K-tile into Bs[BUF]: 4 x gload16/thread, 32-bit offsets
#define STAGE(C, JB, BUF)                                                      \
  {                                                                            \
    const unsigned _cb = ((unsigned)(C) << 16) + (unsigned)(JB);               \
    _Pragma("unroll") for (int _e = 0; _e < 4; ++_e) {                         \
      gload16(Bp + _cb + stg_off[_e],                                          \
              &Bs[BUF][(size_t)(((_e << 9) | tid)) << 3]);                     \
    }                                                                          \
  }

// compute prefetch target (cn, jbn) for k-tile index nk = ci*4 + K4 + 1
#define NEXT_CJ(K4, CN, JBN)                                                   \
  int _nk = (ci << 2) + (K4) + 1;                                              \
  if (_nk > nkmax) _nk = nkmax;                                                \
  const int _nci = _nk >> 2;                                                   \
  const int CN = is7 ? (_nci < 32 ? 225 + _nci : 257) : c0 + _nci;             \
  const int JBN = (_nk & 3) << 6;

// one K-tile phase:
// STAGE(next) -> vmcnt(4) -> s_barrier -> ds_reads (B,A[,EXTRA]) ->
// setprio(1) -> 32 MFMA -> setprio(0) -> s_barrier
#define KT(K4, CUR, EXTRA)                                                     \
  {                                                                            \
    NEXT_CJ(K4, _cn, _jbn);                                                    \
    STAGE(_cn, _jbn, (CUR) ^ 1);                                               \
    asm volatile("s_waitcnt vmcnt(4)" ::: "memory");                           \
    __builtin_amdgcn_s_barrier();                                              \
    bf16x8 bf0[4], bf1[4];                                                     \
    _Pragma("unroll") for (int fn = 0; fn < 4; ++fn) {                         \
      const int _rb = (wn << 6) + (fn << 4) + l15;                             \
      const int _rx = _rb & 7;                                                 \
      bf0[fn] = *(const bf16x8*)(&Bs[CUR][_rb * 64 + ((lg ^ _rx) << 3)]);      \
      bf1[fn] = *(const bf16x8*)(&Bs[CUR][_rb * 64 + (((4 + lg) ^ _rx) << 3)]);\
    }                                                                          \
    bf16x8 _aA[4], _aB[4];                                                     \
    _Pragma("unroll") for (int rg = 0; rg < 4; ++rg) {                         \
      const int _ra = wr + (rg << 4) + l15;                                    \
      const int _sx = _ra & 15;                                                \
      _aA[rg] = *(const bf16x8*)(&As[_ra * 256 +                               \
                                     (((((K4) << 3) + lg) ^ _sx) << 3)]);      \
      _aB[rg] = *(const bf16x8*)(&As[_ra * 256 +                               \
                                     (((((K4) << 3) + 4 + lg) ^ _sx) << 3)]);  \
    }                                                                          \
    EXTRA;                                                                     \
    __builtin_amdgcn_s_setprio(1);                                             \
    _Pragma("unroll") for (int rg = 0; rg < 4; ++rg)                           \
      _Pragma("unroll") for (int fn = 0; fn < 4; ++fn) {                       \
        t[rg][fn] = __builtin_amdgcn_mfma_f32_16x16x32_bf16(                   \
            _aA[rg], bf0[fn], t[rg][fn], 0, 0, 0);                             \
        t[rg][fn] = __builtin_amdgcn_mfma_f32_16x16x32_bf16(                   \
            _aB[rg], bf1[fn], t[rg][fn], 0, 0, 0);                             \
      }                                                                        \
    __builtin_amdgcn_s_setprio(0);                                             \
    __builtin_amdgcn_s_barrier();                                              \
  }

__global__ __launch_bounds__(512, 1) void gemm_r9(
    const float* __restrict__ X, const float* __restrict__ Xb,
    const float* __restrict__ Xt, const unsigned short* __restrict__ Bp,
    float* __restrict__ P) {
  __shared__ __align__(16) unsigned short As[128 * 256];    // 64 KB static A
  __shared__ __align__(16) unsigned short Bs[2][256 * 64];  // 2 x 32 KB dbuf
  __shared__ __align__(16) float Ss[33 * 128];              // 16.9 KB scales

  const int tid = threadIdx.x;
  const int rid = blockIdx.x;
  const int slice = rid & 7;   // slice pinned to XCD (rid%8 round-robin)
  const int bx = rid >> 3;
  const int bt0 = bx << 7;
  const bool is7 = (slice == 7);
  // slices 0..6 split c in [0,225): 33,32,32,32,32,32,32 ; slice 7: [225,257)+{257}
  const int c0 = is7 ? 225 : slice * 32 + (slice ? 1 : 0);
  const int nCh = (slice == 0 || is7) ? 33 : 32;
  const int nkmax = (nCh << 2) - 1;

  const int wid = tid >> 6, lane = tid & 63;
  const int wm = wid >> 2, wn = wid & 3;  // 2 (bt) x 4 (o) waves
  const int wr = wm << 6;
  const int l15 = lane & 15, lg = lane >> 4;

  // per-thread STAGE source offsets (row*256 + swizzled-slot*8), 32-bit
  unsigned stg_off[4];
#pragma unroll
  for (int e = 0; e < 4; ++e) {
    const int row = (e << 6) | (tid >> 3);
    const int sl = (tid & 7) ^ (row & 7);
    stg_off[e] = (unsigned)(row * 256 + (sl << 3));
  }

  PACK_AS(Xb);
  // stage scale table: Ss[ci*128 + r] = scale of chunk ci for row bt0+r
  for (int i = tid; i < (nCh << 7); i += 512) {
    const int ci = i >> 7, r = i & 127;
    const int c = is7 ? (ci < 32 ? 225 + ci : 257) : c0 + ci;
    Ss[i] = (c < 256) ? Xt[(size_t)c * 4096 + bt0 + r] : 1.0f;
  }
  STAGE(c0, 0, 0);
  __syncthreads();

  f32x4 acc[4][4] = {};

  for (int ci = 0; ci < nCh; ++ci) {
    f32x4 t[4][4] = {};
    f32x4 s4[4];
    KT(0, 0, {});
    KT(1, 1, {});
    KT(2, 0, {});
    KT(3, 1, {
      _Pragma("unroll") for (int rg = 0; rg < 4; ++rg)
          s4[rg] = *(const f32x4*)(&Ss[(ci << 7) + wr + (rg << 4) + (lg << 2)]);
    });
#pragma unroll
    for (int rg = 0; rg < 4; ++rg)
#pragma unroll
      for (int fn = 0; fn < 4; ++fn) acc[rg][fn] += s4[rg] * t[rg][fn];

    if (is7 && ci == 31) {  // switch A-operand to X for the c=257 chunk
      __syncthreads();
      PACK_AS(X);
      __syncthreads();
    }
  }

  // ---- epilogue: C layout col = lane&15, row = (lane>>4)*4 + reg
  float* pp = P + ((size_t)slice << 20);
#pragma unroll
  for (int rg = 0; rg < 4; ++rg) {
    const int row = bt0 + wr + (rg << 4) + (lg << 2);
#pragma unroll
    for (int fn = 0; fn < 4; ++fn) {
      const int col = (wn << 6) + (fn << 4) + l15;
#pragma unroll
      for (int e = 0; e < 4; ++e)
        pp[(size_t)(row + e) * 256 + col] = acc[rg][fn][e];
    }
  }
}

// ---- reduce: sum 8 partial slices + bias + W[o,0]
__global__ void reduce_k(const float* __restrict__ P, const float* __restrict__ W,
                         const float* __restrict__ b, float* __restrict__ out,
                         int nsl) {
  const int idx = blockIdx.x * 256 + threadIdx.x;
  const int o = idx & 255;
  float v = b[o] + W[(size_t)o * DI];
  for (int s = 0; s < nsl; ++s) v += P[idx + (size_t)s * 1048576];
  out[idx] = v;
}

// ================= fallback path (tiny ws): R2 proven kernels ================
__global__ void init_k(const float* __restrict__ W, const float* __restrict__ b,
                       float* __restrict__ out) {
  const int idx = blockIdx.x * 256 + threadIdx.x;
  const int o = idx & 255;
  out[idx] = b[o] + W[(size_t)o * DI];
}

__global__ __launch_bounds__(256, 4) void gemm_fb(
    const float* __restrict__ X, const float* __restrict__ Xa,
    const float* __restrict__ W, float* __restrict__ Out) {
  __shared__ __align__(16) unsigned short Asf[128 * 64];
  __shared__ __align__(16) unsigned short Bsf[128 * 64];
  const int tid = threadIdx.x;
  const int bx = blockIdx.x, by = blockIdx.y, bz = blockIdx.z;
  const int S = gridDim.z;
  const int bt0 = bx << 7, o0 = by << 7;
  const int q = 258 / S, r = 258 % S;
  const int c0 = bz * q + (bz < r ? bz : r);
  const int ccnt = q + (bz < r ? 1 : 0);
  const int nK = ccnt << 2;
  const int wid = tid >> 6, lane = tid & 63;
  const int wr = (wid >> 1) << 6, wc = (wid & 1) << 6;
  const int ar = tid >> 1;
  const int ah = (tid & 1) << 5;
  const float* xrow = X + (size_t)(bt0 + ar) * 256;
  const float* varow = Xa + (size_t)(bt0 + ar) * 256;
  f32x4 acc[4][4] = {};
  for (int kt = 0; kt < nK; ++kt) {
    const int c = c0 + (kt >> 2);
    const int j0 = (kt & 3) << 6;
    __syncthreads();
    {
      const float* vs = (c == 257) ? xrow : varow;
      float s = 1.0f;
      if (c < 256) s = xrow[c];
      const f32x4* vp = (const f32x4*)(vs + j0 + ah);
      f32x4 v[8];
#pragma unroll
      for (int qq = 0; qq < 8; ++qq) v[qq] = vp[qq];
      unsigned short* aw = Asf + ar * 64;
      const int sl0 = ah >> 3, sx = ar & 7;
#pragma unroll
      for (int w = 0; w < 4; ++w) {
        bf16x8 pk;
#pragma unroll
        for (int e = 0; e < 8; ++e)
          pk[e] = (short)f2b(s * v[w * 2 + (e >> 2)][e & 3]);
        *(bf16x8*)(aw + (((sl0 + w) ^ sx) << 3)) = pk;
      }
    }
    {
      const int orow = tid >> 1;
      const int jh = (tid & 1) << 5;
      const float* wrow = W + (size_t)(o0 + orow) * DI;
      float tmp[32];
      if (c < 256) {
        const int bse = (c + 1) * 257 + 1 + j0 + jh;
#pragma unroll
        for (int i = 0; i < 32; ++i) tmp[i] = wrow[bse + i];
      } else if (c == 256) {
        const int bse = 1 + j0 + jh;
#pragma unroll
        for (int i = 0; i < 32; ++i) tmp[i] = wrow[bse + i];
      } else {
#pragma unroll
        for (int i = 0; i < 32; ++i) tmp[i] = wrow[(j0 + jh + i + 1) * 257];
      }
      unsigned short* bw = Bsf + orow * 64;
      const int sl0 = jh >> 3, sx = orow & 7;
#pragma unroll
      for (int w = 0; w < 4; ++w) {
        bf16x8 pk;
#pragma unroll
        for (int e = 0; e < 8; ++e) pk[e] = (short)f2b(tmp[w * 8 + e]);
        *(bf16x8*)(bw + (((sl0 + w) ^ sx) << 3)) = pk;
      }
    }
    __syncthreads();
#pragma unroll
    for (int kk = 0; kk < 2; ++kk) {
      const int kslot = (kk << 2) + (lane >> 4);
      bf16x8 af[4], bfr2[4];
#pragma unroll
      for (int fm = 0; fm < 4; ++fm) {
        const int row = wr + (fm << 4) + (lane & 15);
        af[fm] = *(const bf16x8*)(Asf + row * 64 + ((kslot ^ (row & 7)) << 3));
      }
#pragma unroll
      for (int fn = 0; fn < 4; ++fn) {
        const int row = wc + (fn << 4) + (lane & 15);
        bfr2[fn] = *(const bf16x8*)(Bsf + row * 64 + ((kslot ^ (row & 7)) << 3));
      }
#pragma unroll
      for (int fm = 0; fm < 4; ++fm)
#pragma unroll
        for (int fn = 0; fn < 4; ++fn)
          acc[fm][fn] = __builtin_amdgcn_mfma_f32_16x16x32_bf16(
              af[fm], bfr2[fn], acc[fm][fn], 0, 0, 0);
    }
  }
  const int r0 = (lane >> 4) << 2;
  const int cl = lane & 15;
#pragma unroll
  for (int fm = 0; fm < 4; ++fm) {
    const int row = bt0 + wr + (fm << 4) + r0;
#pragma unroll
    for (int fn = 0; fn < 4; ++fn) {
      const int col = o0 + wc + (fn << 4) + cl;
#pragma unroll
      for (int rr = 0; rr < 4; ++rr)
        atomicAdd(Out + (size_t)(row + rr) * 256 + col, acc[fm][fn][rr]);
    }
  }
}

extern "C" void kernel_launch(void* const* d_in, const int* in_sizes, int n_in,
                              void* d_out, int out_size, void* d_ws, size_t ws_size,
                              hipStream_t stream) {
  const float* X  = (const float*)d_in[0];
  const float* Xa = (const float*)d_in[1];
  const float* W  = (const float*)d_in[2];
  const float* b  = (const float*)d_in[3];
  float* out = (float*)d_out;

  const size_t WBF_SZ = (size_t)258 * 256 * 256 * 2;  // 33,816,576 B
  const size_t XT_SZ  = (size_t)256 * 4096 * 4;       //  4,194,304 B
  const size_t PART1  = (size_t)4096 * 256 * 4;       //  4 MiB per slice

  if (ws_size >= WBF_SZ + XT_SZ + 8 * PART1) {
    unsigned short* Bp = (unsigned short*)d_ws;
    float* Xt = (float*)((char*)d_ws + WBF_SZ);
    float* P  = (float*)((char*)d_ws + WBF_SZ + XT_SZ);
    prep_w<<<dim3(258, 64), 256, 0, stream>>>(W, Bp);
    prep_xt<<<dim3(128, 8), dim3(32, 8), 0, stream>>>(X, Xt);
    gemm_r9<<<dim3(256), 512, 0, stream>>>(X, Xa, Xt, Bp, P);
    reduce_k<<<4096, 256, 0, stream>>>(P, W, b, out, 8);
  } else {
    init_k<<<4096, 256, 0, stream>>>(W, b, out);
    gemm_fb<<<dim3(32, 2, 4), 256, 0, stream>>>(X, Xa, W, out);
  }
}

// Round 10
// 174.273 us; speedup vs baseline: 1.1472x; 1.0544x over previous
//
#include <hip/hip_runtime.h>
#include <hip/hip_bf16.h>

// out[bt,o] = b[o] + sum_{i,j} Xa[bt,i]*Xb[bt,j]*W[o, i*257+j], Xa=[1,X], Xb=[1,X_aux]
// Chunk c in [0,258):
//   c<256 : contrib = X[r,c] * sum_j Xb[r,j]*Bp[c][o][j]
//   c=256 : contrib =          sum_j Xb[r,j]*Bp[256][o][j]
//   c=257 : contrib =          sum_j X [r,j]*Bp[257][o][j]
// k=0 corner (W[o,0]) folded into reduce with bias.
//
// R10: decoupled read/MFMA pipeline at K=32 "unit" granularity (m201 style).
// Per unit: STAGE(u+3) -> vmcnt(4) -> barrier -> ds_read frags(u+1) into the
// spare register set -> 16 MFMA on the set loaded last unit (LDS pipe overlaps
// MFMA drain). Bs = ring of 4 x 16KB (K=32) buffers, swizzle slot^((row>>1)&3)
// (2-way free). Slices 0-6: c in [32s,32s+32); slice 7: [224,257) (c=256 via
// Ss=1, no As repack). c=257 handled by 32 extra blocks (As=X, P slice 8).
// Registers/wave (2 waves/SIMD cap 256): acc 64 + t 64 + frag dbuf 64 + misc.

#define DI 66049

typedef __attribute__((ext_vector_type(8))) short bf16x8;
typedef __attribute__((ext_vector_type(4))) float f32x4;

__device__ __forceinline__ unsigned short f2b(float f) {
  union { __hip_bfloat16 h; unsigned short u; } cv;
  cv.h = __float2bfloat16(f);
  return cv.u;
}

__device__ __forceinline__ bf16x8 pack8(f32x4 lo, f32x4 hi) {
  bf16x8 r;
  r[0] = (short)f2b(lo[0]); r[1] = (short)f2b(lo[1]);
  r[2] = (short)f2b(lo[2]); r[3] = (short)f2b(lo[3]);
  r[4] = (short)f2b(hi[0]); r[5] = (short)f2b(hi[1]);
  r[6] = (short)f2b(hi[2]); r[7] = (short)f2b(hi[3]);
  return r;
}

__device__ __forceinline__ void gload16(const void* g, void* l) {
  __builtin_amdgcn_global_load_lds(
      (const __attribute__((address_space(1))) unsigned int*)g,
      (__attribute__((address_space(3))) unsigned int*)l, 16, 0, 0);
}

// ---- prep: gather W (f32) into bf16 Bp[c][o][j] (linear), c in [0,258)
__global__ void prep_w(const float* __restrict__ W, unsigned short* __restrict__ Bp) {
  const int c = blockIdx.x;
  const int o = (blockIdx.y << 2) + (threadIdx.x >> 6);
  const int j = (threadIdx.x & 63) << 2;
  const float* wrow = W + (size_t)o * DI;
  float v0, v1, v2, v3;
  if (c < 256) {
    const int bse = (c + 1) * 257 + 1 + j;
    v0 = wrow[bse]; v1 = wrow[bse + 1]; v2 = wrow[bse + 2]; v3 = wrow[bse + 3];
  } else if (c == 256) {
    const int bse = 1 + j;
    v0 = wrow[bse]; v1 = wrow[bse + 1]; v2 = wrow[bse + 2]; v3 = wrow[bse + 3];
  } else {
    v0 = wrow[(j + 1) * 257]; v1 = wrow[(j + 2) * 257];
    v2 = wrow[(j + 3) * 257]; v3 = wrow[(j + 4) * 257];
  }
  unsigned short* dst = Bp + (((size_t)c << 8) + o) * 256 + j;
  const unsigned int lo = (unsigned int)f2b(v0) | ((unsigned int)f2b(v1) << 16);
  const unsigned int hi = (unsigned int)f2b(v2) | ((unsigned int)f2b(v3) << 16);
  *(uint2*)dst = make_uint2(lo, hi);
}

// ---- prep: Xt[c][bt] = X[bt][c]  (f32 transpose for coalesced scale loads)
__global__ void prep_xt(const float* __restrict__ X, float* __restrict__ Xt) {
  __shared__ float t[32][33];
  const int tx = threadIdx.x, ty = threadIdx.y;
  const int bt0 = blockIdx.x << 5, c0 = blockIdx.y << 5;
#pragma unroll
  for (int k = 0; k < 4; ++k) {
    const int row = (ty << 2) + k;
    t[row][tx] = X[(size_t)(bt0 + row) * 256 + c0 + tx];
  }
  __syncthreads();
#pragma unroll
  for (int k = 0; k < 4; ++k) {
    const int row = (ty << 2) + k;
    Xt[(size_t)(c0 + row) * 4096 + bt0 + tx] = t[tx][row];
  }
}

// pack As[128][256] bf16 from SRC rows [bt0,bt0+128), 16-slot XOR swizzle
#define PACK_AS(SRC)                                                           \
  {                                                                            \
    const int _row = tid >> 2, _q = tid & 3;                                   \
    const float* _rp = (SRC) + (size_t)(bt0 + _row) * 256 + (_q << 6);         \
    const int _sx = _row & 15;                                                 \
    _Pragma("unroll") for (int _w = 0; _w < 8; ++_w) {                         \
      f32x4 _lo = *(const f32x4*)(_rp + (_w << 3));                            \
      f32x4 _hi = *(const f32x4*)(_rp + (_w << 3) + 4);                        \
      const int _slot = (_q << 3) + _w;                                        \
      *(bf16x8*)(&As[_row * 256 + ((_slot ^ _sx) << 3)]) = pack8(_lo, _hi);    \
    }                                                                          \
  }

// stage one K=32 unit V into Bs[SLOT]: 2 x gload16/thread, 32-bit offsets
#define STAGE_U(V, SLOT)                                                       \
  {                                                                            \
    const unsigned short* _bse =                                               \
        Bp + ((size_t)(c0 + ((V) >> 3)) << 16) + (((V) & 7) << 5);             \
    gload16(_bse + stg_off0, &Bs[SLOT][(size_t)tid << 3]);                     \
    gload16(_bse + stg_off1, &Bs[SLOT][(size_t)(512 + tid) << 3]);             \
  }

// read fragment set S for unit U (4 A-frags from As, 4 B-frags from ring)
#define READ_FRAGS(U, S)                                                       \
  {                                                                            \
    const int _uh4 = ((U) & 7) << 2;                                           \
    _Pragma("unroll") for (int _rg = 0; _rg < 4; ++_rg) {                      \
      const int _ra = wr + (_rg << 4) + l15;                                   \
      fa[S][_rg] = *(const bf16x8*)(&As[_ra * 256 +                            \
                                        (((_uh4 + lg) ^ (_ra & 15)) << 3)]);   \
    }                                                                          \
    _Pragma("unroll") for (int _fn = 0; _fn < 4; ++_fn) {                      \
      const int _rb = (wn << 6) + (_fn << 4) + l15;                            \
      fb[S][_fn] = *(const bf16x8*)(&Bs[(U) & 3][_rb * 32 +                    \
                                        ((lg ^ ((_rb >> 1) & 3)) << 3)]);      \
    }                                                                          \
  }

__global__ __launch_bounds__(512, 1) void gemm_r10(
    const float* __restrict__ X, const float* __restrict__ Xb,
    const float* __restrict__ Xt, const unsigned short* __restrict__ Bp,
    float* __restrict__ P) {
  __shared__ __align__(16) unsigned short As[128 * 256];   // 64 KB static A
  __shared__ __align__(16) unsigned short Bs[4][256 * 32]; // 4 x 16 KB ring
  __shared__ __align__(16) float Ss[33 * 128];             // 16.9 KB scales

  const int tid = threadIdx.x;
  const int rid = blockIdx.x;

  int bx, c0, nCh, Pslice;
  const float* Asrc;
  if (rid < 256) {                 // main slices, XCD-pinned by rid&7
    const int slice = rid & 7;
    bx = rid >> 3;
    c0 = slice << 5;
    nCh = (slice == 7) ? 33 : 32;  // slice 7 covers c in [224,257)
    Asrc = Xb;
    Pslice = slice;
  } else {                         // c = 257 blocks (A = X)
    bx = rid - 256;
    c0 = 257;
    nCh = 1;
    Asrc = X;
    Pslice = 8;
  }
  const int bt0 = bx << 7;
  const int nU = nCh << 3;

  const int wid = tid >> 6, lane = tid & 63;
  const int wm = wid >> 2, wn = wid & 3;  // 2 (bt) x 4 (o) waves
  const int wr = wm << 6;
  const int l15 = lane & 15, lg = lane >> 4;

  // per-thread STAGE source offsets (pre-swizzled col group), 32-bit
  const int idx0 = tid, idx1 = 512 + tid;
  const int row0 = idx0 >> 2, row1 = idx1 >> 2;
  const unsigned stg_off0 =
      (unsigned)(row0 * 256 + (((idx0 & 3) ^ ((row0 >> 1) & 3)) << 3));
  const unsigned stg_off1 =
      (unsigned)(row1 * 256 + (((idx1 & 3) ^ ((row1 >> 1) & 3)) << 3));

  PACK_AS(Asrc);
  // scale table: Ss[ci*128 + r] = X[bt0+r, c0+ci] (1.0 for c >= 256)
  for (int i = tid; i < (nCh << 7); i += 512) {
    const int ci2 = i >> 7, r = i & 127;
    const int c = c0 + ci2;
    Ss[i] = (c < 256) ? Xt[(size_t)c * 4096 + bt0 + r] : 1.0f;
  }
  STAGE_U(0, 0);
  STAGE_U(1, 1);
  STAGE_U(2, 2);
  __syncthreads();  // full drain: As/Ss visible, stages 0-2 complete

  bf16x8 fa[2][4], fb[2][4];
  READ_FRAGS(0, 0);

  f32x4 acc[4][4] = {};

  for (int ci = 0; ci < nCh; ++ci) {
    f32x4 t[4][4] = {};
    f32x4 s4[4];
#pragma unroll
    for (int uh = 0; uh < 8; ++uh) {
      const int u = (ci << 3) + uh;
      int v = u + 3;
      if (v > nU - 1) v = nU - 1;           // clamp (writes unread ring slot)
      STAGE_U(v, (u + 3) & 3);
      asm volatile("s_waitcnt vmcnt(4)" ::: "memory");  // stage(u+1) done
      __builtin_amdgcn_s_barrier();
      int un = u + 1;
      if (un > nU - 1) un = nU - 1;         // clamp (result unused)
      if (uh & 1) {
        READ_FRAGS(un, 0);
      } else {
        READ_FRAGS(un, 1);
      }
      if (uh == 7) {
#pragma unroll
        for (int rg = 0; rg < 4; ++rg)
          s4[rg] =
              *(const f32x4*)(&Ss[(ci << 7) + wr + (rg << 4) + (lg << 2)]);
      }
      __builtin_amdgcn_s_setprio(1);
#pragma unroll
      for (int rg = 0; rg < 4; ++rg)
#pragma unroll
        for (int fn = 0; fn < 4; ++fn)
          t[rg][fn] = (uh & 1)
                          ? __builtin_amdgcn_mfma_f32_16x16x32_bf16(
                                fa[1][rg], fb[1][fn], t[rg][fn], 0, 0, 0)
                          : __builtin_amdgcn_mfma_f32_16x16x32_bf16(
                                fa[0][rg], fb[0][fn], t[rg][fn], 0, 0, 0);
      __builtin_amdgcn_s_setprio(0);
    }
#pragma unroll
    for (int rg = 0; rg < 4; ++rg)
#pragma unroll
      for (int fn = 0; fn < 4; ++fn) acc[rg][fn] += s4[rg] * t[rg][fn];
  }

  // ---- epilogue: C layout col = lane&15, row = (lane>>4)*4 + reg
  float* pp = P + ((size_t)Pslice << 20);
#pragma unroll
  for (int rg = 0; rg < 4; ++rg) {
    const int row = bt0 + wr + (rg << 4) + (lg << 2);
#pragma unroll
    for (int fn = 0; fn < 4; ++fn) {
      const int col = (wn << 6) + (fn << 4) + l15;
#pragma unroll
      for (int e = 0; e < 4; ++e)
        pp[(size_t)(row + e) * 256 + col] = acc[rg][fn][e];
    }
  }
}

// ---- reduce: sum 9 partial slices + bias + W[o,0]
__global__ void reduce_k(const float* __restrict__ P, const float* __restrict__ W,
                         const float* __restrict__ b, float* __restrict__ out,
                         int nsl) {
  const int idx = blockIdx.x * 256 + threadIdx.x;
  const int o = idx & 255;
  float v = b[o] + W[(size_t)o * DI];
  for (int s = 0; s < nsl; ++s) v += P[idx + (size_t)s * 1048576];
  out[idx] = v;
}

// ================= fallback path (tiny ws): R2 proven kernels ================
__global__ void init_k(const float* __restrict__ W, const float* __restrict__ b,
                       float* __restrict__ out) {
  const int idx = blockIdx.x * 256 + threadIdx.x;
  const int o = idx & 255;
  out[idx] = b[o] + W[(size_t)o * DI];
}

__global__ __launch_bounds__(256, 4) void gemm_fb(
    const float* __restrict__ X, const float* __restrict__ Xa,
    const float* __restrict__ W, float* __restrict__ Out) {
  __shared__ __align__(16) unsigned short Asf[128 * 64];
  __shared__ __align__(16) unsigned short Bsf[128 * 64];
  const int tid = threadIdx.x;
  const int bx = blockIdx.x, by = blockIdx.y, bz = blockIdx.z;
  const int S = gridDim.z;
  const int bt0 = bx << 7, o0 = by << 7;
  const int q = 258 / S, r = 258 % S;
  const int c0 = bz * q + (bz < r ? bz : r);
  const int ccnt = q + (bz < r ? 1 : 0);
  const int nK = ccnt << 2;
  const int wid = tid >> 6, lane = tid & 63;
  const int wr = (wid >> 1) << 6, wc = (wid & 1) << 6;
  const int ar = tid >> 1;
  const int ah = (tid & 1) << 5;
  const float* xrow = X + (size_t)(bt0 + ar) * 256;
  const float* varow = Xa + (size_t)(bt0 + ar) * 256;
  f32x4 acc[4][4] = {};
  for (int kt = 0; kt < nK; ++kt) {
    const int c = c0 + (kt >> 2);
    const int j0 = (kt & 3) << 6;
    __syncthreads();
    {
      const float* vs = (c == 257) ? xrow : varow;
      float s = 1.0f;
      if (c < 256) s = xrow[c];
      const f32x4* vp = (const f32x4*)(vs + j0 + ah);
      f32x4 v[8];
#pragma unroll
      for (int qq = 0; qq < 8; ++qq) v[qq] = vp[qq];
      unsigned short* aw = Asf + ar * 64;
      const int sl0 = ah >> 3, sx = ar & 7;
#pragma unroll
      for (int w = 0; w < 4; ++w) {
        bf16x8 pk;
#pragma unroll
        for (int e = 0; e < 8; ++e)
          pk[e] = (short)f2b(s * v[w * 2 + (e >> 2)][e & 3]);
        *(bf16x8*)(aw + (((sl0 + w) ^ sx) << 3)) = pk;
      }
    }
    {
      const int orow = tid >> 1;
      const int jh = (tid & 1) << 5;
      const float* wrow = W + (size_t)(o0 + orow) * DI;
      float tmp[32];
      if (c < 256) {
        const int bse = (c + 1) * 257 + 1 + j0 + jh;
#pragma unroll
        for (int i = 0; i < 32; ++i) tmp[i] = wrow[bse + i];
      } else if (c == 256) {
        const int bse = 1 + j0 + jh;
#pragma unroll
        for (int i = 0; i < 32; ++i) tmp[i] = wrow[bse + i];
      } else {
#pragma unroll
        for (int i = 0; i < 32; ++i) tmp[i] = wrow[(j0 + jh + i + 1) * 257];
      }
      unsigned short* bw = Bsf + orow * 64;
      const int sl0 = jh >> 3, sx = orow & 7;
#pragma unroll
      for (int w = 0; w < 4; ++w) {
        bf16x8 pk;
#pragma unroll
        for (int e = 0; e < 8; ++e) pk[e] = (short)f2b(tmp[w * 8 + e]);
        *(bf16x8*)(bw + (((sl0 + w) ^ sx) << 3)) = pk;
      }
    }
    __syncthreads();
#pragma unroll
    for (int kk = 0; kk < 2; ++kk) {
      const int kslot = (kk << 2) + (lane >> 4);
      bf16x8 af[4], bfr2[4];
#pragma unroll
      for (int fm = 0; fm < 4; ++fm) {
        const int row = wr + (fm << 4) + (lane & 15);
        af[fm] = *(const bf16x8*)(Asf + row * 64 + ((kslot ^ (row & 7)) << 3));
      }
#pragma unroll
      for (int fn = 0; fn < 4; ++fn) {
        const int row = wc + (fn << 4) + (lane & 15);
        bfr2[fn] = *(const bf16x8*)(Bsf + row * 64 + ((kslot ^ (row & 7)) << 3));
      }
#pragma unroll
      for (int fm = 0; fm < 4; ++fm)
#pragma unroll
        for (int fn = 0; fn < 4; ++fn)
          acc[fm][fn] = __builtin_amdgcn_mfma_f32_16x16x32_bf16(
              af[fm], bfr2[fn], acc[fm][fn], 0, 0, 0);
    }
  }
  const int r0 = (lane >> 4) << 2;
  const int cl = lane & 15;
#pragma unroll
  for (int fm = 0; fm < 4; ++fm) {
    const int row = bt0 + wr + (fm << 4) + r0;
#pragma unroll
    for (int fn = 0; fn < 4; ++fn) {
      const int col = o0 + wc + (fn << 4) + cl;
#pragma unroll
      for (int rr = 0; rr < 4; ++rr)
        atomicAdd(Out + (size_t)(row + rr) * 256 + col, acc[fm][fn][rr]);
    }
  }
}

extern "C" void kernel_launch(void* const* d_in, const int* in_sizes, int n_in,
                              void* d_out, int out_size, void* d_ws, size_t ws_size,
                              hipStream_t stream) {
  const float* X  = (const float*)d_in[0];
  const float* Xa = (const float*)d_in[1];
  const float* W  = (const float*)d_in[2];
  const float* b  = (const float*)d_in[3];
  float* out = (float*)d_out;

  const size_t WBF_SZ = (size_t)258 * 256 * 256 * 2;  // 33,816,576 B
  const size_t XT_SZ  = (size_t)256 * 4096 * 4;       //  4,194,304 B
  const size_t PART1  = (size_t)4096 * 256 * 4;       //  4 MiB per slice

  if (ws_size >= WBF_SZ + XT_SZ + 9 * PART1) {
    unsigned short* Bp = (unsigned short*)d_ws;
    float* Xt = (float*)((char*)d_ws + WBF_SZ);
    float* P  = (float*)((char*)d_ws + WBF_SZ + XT_SZ);
    prep_w<<<dim3(258, 64), 256, 0, stream>>>(W, Bp);
    prep_xt<<<dim3(128, 8), dim3(32, 8), 0, stream>>>(X, Xt);
    gemm_r10<<<dim3(288), 512, 0, stream>>>(X, Xa, Xt, Bp, P);
    reduce_k<<<4096, 256, 0, stream>>>(P, W, b, out, 9);
  } else {
    init_k<<<4096, 256, 0, stream>>>(W, b, out);
    gemm_fb<<<dim3(32, 2, 4), 256, 0, stream>>>(X, Xa, W, out);
  }
}